// Round 12
// baseline (1106.084 us; speedup 1.0000x reference)
//
#include <hip/hip_runtime.h>
#include <hip/hip_bf16.h>
#include <math.h>

// Problem dims
#define VV   32000
#define DIM  256
#define BB   4
#define SS   512
#define TT   256
#define D2   512
#define D3   768

typedef __attribute__((ext_vector_type(8))) short s16x8;
typedef __attribute__((ext_vector_type(4))) float f32x4;

__device__ __forceinline__ float rcp_(float x) { return __builtin_amdgcn_rcpf(x); }
__device__ __forceinline__ float sigmoidf_(float x) { return rcp_(1.0f + __expf(-x)); }
// precise forms for the GRU epilogue (R6's 680us config)
__device__ __forceinline__ float sigmoid_p(float x) { return 1.0f / (1.0f + __expf(-x)); }
__device__ __forceinline__ float tanh_p(float x) {
    float e2 = __expf(2.0f * x);
    return (e2 - 1.0f) / (e2 + 1.0f);
}
__device__ __forceinline__ short f2bf(float f) {  // RNE f32->bf16
    unsigned u = __float_as_uint(f);
    u += 0x7FFFu + ((u >> 16) & 1u);
    return (short)(u >> 16);
}
__device__ __forceinline__ float bf2f(short s) {
    return __uint_as_float(((unsigned)(unsigned short)s) << 16);
}

// R4-proven barrier: lgkm-only drain keeps global loads/stores in flight.
#define BAR_LGKM() asm volatile("s_waitcnt lgkmcnt(0)\n\ts_barrier" ::: "memory")

// ---------------------------------------------------------------------------
// Input projections with FUSED embedding: C[M,768] = (emb[tok]+pos) @ W^T + b.
// ---------------------------------------------------------------------------
struct PDesc {
    const int* tok;
    const float* Wt;
    const float* bias;
    float* C;
    int M;
    int lmask;
};

__global__ __launch_bounds__(512) void k_proj(const float* __restrict__ emb,
                                              const float* __restrict__ pos,
                                              PDesc p0, PDesc p1, PDesc p2) {
    PDesc p = (blockIdx.z == 0) ? p0 : ((blockIdx.z == 1) ? p1 : p2);
    int brow = blockIdx.y * 256;
    if (brow >= p.M) return;
    int bcol = blockIdx.x * 128;

    __shared__ __align__(16) short As[256 * 32];
    __shared__ __align__(16) short Bs[128 * 32];
    int tid = threadIdx.x;
    int lane = tid & 63, wv = tid >> 6;
    int wm = wv >> 1, wn = wv & 1;
    const int ll = lane & 15, lh = lane >> 4;

    f32x4 acc[4][4];
#pragma unroll
    for (int i = 0; i < 4; i++)
#pragma unroll
        for (int j = 0; j < 4; j++) acc[i][j] = (f32x4){0.f, 0.f, 0.f, 0.f};

    const int ar = tid >> 1, ak = (tid & 1) * 16;
    const int br = tid >> 2, bk = (tid & 3) * 8;
    const int grow = brow + ar;
    const float* erow = emb + (size_t)p.tok[grow] * DIM;
    const float* prow = pos + (size_t)(grow & p.lmask) * DIM;

    for (int k0 = 0; k0 < DIM; k0 += 32) {
        float4 a0 = *(const float4*)(erow + k0 + ak);
        float4 a1 = *(const float4*)(erow + k0 + ak + 4);
        float4 a2 = *(const float4*)(erow + k0 + ak + 8);
        float4 a3 = *(const float4*)(erow + k0 + ak + 12);
        float4 q0 = *(const float4*)(prow + k0 + ak);
        float4 q1 = *(const float4*)(prow + k0 + ak + 4);
        float4 q2 = *(const float4*)(prow + k0 + ak + 8);
        float4 q3 = *(const float4*)(prow + k0 + ak + 12);
        const float* bp = &p.Wt[(size_t)(bcol + br) * DIM + k0 + bk];
        float4 b0 = *(const float4*)bp;
        float4 b1 = *(const float4*)(bp + 4);
        s16x8 va0, va1, vb;
        va0[0] = f2bf(a0.x + q0.x); va0[1] = f2bf(a0.y + q0.y);
        va0[2] = f2bf(a0.z + q0.z); va0[3] = f2bf(a0.w + q0.w);
        va0[4] = f2bf(a1.x + q1.x); va0[5] = f2bf(a1.y + q1.y);
        va0[6] = f2bf(a1.z + q1.z); va0[7] = f2bf(a1.w + q1.w);
        va1[0] = f2bf(a2.x + q2.x); va1[1] = f2bf(a2.y + q2.y);
        va1[2] = f2bf(a2.z + q2.z); va1[3] = f2bf(a2.w + q2.w);
        va1[4] = f2bf(a3.x + q3.x); va1[5] = f2bf(a3.y + q3.y);
        va1[6] = f2bf(a3.z + q3.z); va1[7] = f2bf(a3.w + q3.w);
        vb[0] = f2bf(b0.x); vb[1] = f2bf(b0.y); vb[2] = f2bf(b0.z); vb[3] = f2bf(b0.w);
        vb[4] = f2bf(b1.x); vb[5] = f2bf(b1.y); vb[6] = f2bf(b1.z); vb[7] = f2bf(b1.w);

        __syncthreads();
        *(s16x8*)&As[ar * 32 + ak] = va0;
        *(s16x8*)&As[ar * 32 + ak + 8] = va1;
        *(s16x8*)&Bs[br * 32 + bk] = vb;
        __syncthreads();

        s16x8 af[4], bf[4];
#pragma unroll
        for (int mt = 0; mt < 4; ++mt)
            af[mt] = *(const s16x8*)&As[(wm * 64 + mt * 16 + ll) * 32 + lh * 8];
#pragma unroll
        for (int nt = 0; nt < 4; ++nt)
            bf[nt] = *(const s16x8*)&Bs[(wn * 64 + nt * 16 + ll) * 32 + lh * 8];
#pragma unroll
        for (int mt = 0; mt < 4; ++mt)
#pragma unroll
            for (int nt = 0; nt < 4; ++nt)
                acc[mt][nt] = __builtin_amdgcn_mfma_f32_16x16x32_bf16(af[mt], bf[nt], acc[mt][nt], 0, 0, 0);
    }

#pragma unroll
    for (int mt = 0; mt < 4; ++mt) {
        int row = brow + wm * 64 + mt * 16 + lh * 4;
#pragma unroll
        for (int nt = 0; nt < 4; ++nt) {
            int col = bcol + wn * 64 + nt * 16 + ll;
            float bv = p.bias[col];
#pragma unroll
            for (int q = 0; q < 4; ++q)
                p.C[(size_t)(row + q) * D3 + col] = acc[mt][nt][q] + bv;
        }
    }
}

// ---------------------------------------------------------------------------
// Q/K projections as bf16 MFMA.
// ---------------------------------------------------------------------------
struct QDesc {
    const float* A; int K;
    const float* Bt;
    float* C;
    int M;
};

__global__ __launch_bounds__(512) void k_qk(QDesc q0d, QDesc q1d) {
    QDesc p = (blockIdx.z == 0) ? q0d : q1d;
    int brow = blockIdx.y * 256;
    if (brow >= p.M) return;
    int bcol = blockIdx.x * 128;
    const int K = p.K;

    __shared__ __align__(16) short As[256 * 32];
    __shared__ __align__(16) short Bs[128 * 32];
    int tid = threadIdx.x;
    int lane = tid & 63, wv = tid >> 6;
    int wm = wv >> 1, wn = wv & 1;
    const int ll = lane & 15, lh = lane >> 4;

    f32x4 acc[4][4];
#pragma unroll
    for (int i = 0; i < 4; i++)
#pragma unroll
        for (int j = 0; j < 4; j++) acc[i][j] = (f32x4){0.f, 0.f, 0.f, 0.f};

    const int ar = tid >> 1, ak = (tid & 1) * 16;
    const int br = tid >> 2, bk = (tid & 3) * 8;

    for (int k0 = 0; k0 < K; k0 += 32) {
        const float* ap = &p.A[(size_t)(brow + ar) * K + k0 + ak];
        float4 a0 = *(const float4*)ap;
        float4 a1 = *(const float4*)(ap + 4);
        float4 a2 = *(const float4*)(ap + 8);
        float4 a3 = *(const float4*)(ap + 12);
        const float* bp = &p.Bt[(size_t)(bcol + br) * K + k0 + bk];
        float4 b0 = *(const float4*)bp;
        float4 b1 = *(const float4*)(bp + 4);
        s16x8 va0, va1, vb;
        va0[0] = f2bf(a0.x); va0[1] = f2bf(a0.y); va0[2] = f2bf(a0.z); va0[3] = f2bf(a0.w);
        va0[4] = f2bf(a1.x); va0[5] = f2bf(a1.y); va0[6] = f2bf(a1.z); va0[7] = f2bf(a1.w);
        va1[0] = f2bf(a2.x); va1[1] = f2bf(a2.y); va1[2] = f2bf(a2.z); va1[3] = f2bf(a2.w);
        va1[4] = f2bf(a3.x); va1[5] = f2bf(a3.y); va1[6] = f2bf(a3.z); va1[7] = f2bf(a3.w);
        vb[0] = f2bf(b0.x); vb[1] = f2bf(b0.y); vb[2] = f2bf(b0.z); vb[3] = f2bf(b0.w);
        vb[4] = f2bf(b1.x); vb[5] = f2bf(b1.y); vb[6] = f2bf(b1.z); vb[7] = f2bf(b1.w);

        __syncthreads();
        *(s16x8*)&As[ar * 32 + ak] = va0;
        *(s16x8*)&As[ar * 32 + ak + 8] = va1;
        *(s16x8*)&Bs[br * 32 + bk] = vb;
        __syncthreads();

        s16x8 af[4], bf[4];
#pragma unroll
        for (int mt = 0; mt < 4; ++mt)
            af[mt] = *(const s16x8*)&As[(wm * 64 + mt * 16 + ll) * 32 + lh * 8];
#pragma unroll
        for (int nt = 0; nt < 4; ++nt)
            bf[nt] = *(const s16x8*)&Bs[(wn * 64 + nt * 16 + ll) * 32 + lh * 8];
#pragma unroll
        for (int mt = 0; mt < 4; ++mt)
#pragma unroll
            for (int nt = 0; nt < 4; ++nt)
                acc[mt][nt] = __builtin_amdgcn_mfma_f32_16x16x32_bf16(af[mt], bf[nt], acc[mt][nt], 0, 0, 0);
    }

#pragma unroll
    for (int mt = 0; mt < 4; ++mt) {
        int row = brow + wm * 64 + mt * 16 + lh * 4;
#pragma unroll
        for (int nt = 0; nt < 4; ++nt) {
            int col = bcol + wn * 64 + nt * 16 + ll;
#pragma unroll
            for (int q = 0; q < 4; ++q)
                p.C[(size_t)(row + q) * DIM + col] = acc[mt][nt][q];
        }
    }
}

// ---------------------------------------------------------------------------
// GRU recurrences (R6-exact 680us form) + fused Wgen cvt / rowsum zeroing.
// ---------------------------------------------------------------------------
#define HSTRIDE 576
#define HBUF    (4 * HSTRIDE)
#define NCVT8   ((size_t)VV * D3 / 8)

__global__ __launch_bounds__(512, 2) void k_gru(const float* __restrict__ ef_x,
                                                const float* __restrict__ eb_x,
                                                const float* __restrict__ d_x,
                                                const float* __restrict__ ef_whh, const float* __restrict__ ef_bhh,
                                                const float* __restrict__ eb_whh, const float* __restrict__ eb_bhh,
                                                const float* __restrict__ d_whh, const float* __restrict__ d_bhh,
                                                float* __restrict__ enc_out,
                                                float* __restrict__ dec_out,
                                                const float* __restrict__ wgen,
                                                short* __restrict__ wgen_bf,
                                                float* __restrict__ rowsum,
                                                int do_cvt) {
    int tid = threadIdx.x;
    int bid = blockIdx.x;

    if (bid >= 3) {   // fused side-work on otherwise-idle CUs
        int cb = bid - 3;
        if (cb == 0) { rowsum[tid] = 0.0f; rowsum[tid + 512] = 0.0f; }
        if (do_cvt) {
            size_t i = (size_t)cb * 512 + tid;
            if (i < NCVT8) {
                const float4* p = (const float4*)(wgen + i * 8);
                float4 a = p[0], b4 = p[1];
                s16x8 v;
                v[0] = f2bf(a.x); v[1] = f2bf(a.y); v[2] = f2bf(a.z); v[3] = f2bf(a.w);
                v[4] = f2bf(b4.x); v[5] = f2bf(b4.y); v[6] = f2bf(b4.z); v[7] = f2bf(b4.w);
                *(s16x8*)(wgen_bf + i * 8) = v;
            }
        }
        return;
    }

    __shared__ __align__(16) char hb[2 * HBUF];
    int dir = bid;
    const float *xw, *Whh, *bhh;
    int L;
    if (dir == 0)      { xw = ef_x; Whh = ef_whh; bhh = ef_bhh; L = SS; }
    else if (dir == 1) { xw = eb_x; Whh = eb_whh; bhh = eb_bhh; L = SS; }
    else               { xw = d_x;  Whh = d_whh;  bhh = d_bhh;  L = TT; }

    const int wv = tid >> 6;
    const int lane = tid & 63;
    const int jj = lane & 15;
    const int hi = lane >> 4;
    const int b = hi;

    if (tid < 288) {
        f32x4 z = {0.f, 0.f, 0.f, 0.f};
        *(f32x4*)(hb + tid * 16) = z;
    }

    s16x8 wf[3][2][8];
#pragma unroll
    for (int g = 0; g < 3; ++g)
#pragma unroll
        for (int t = 0; t < 2; ++t) {
            const int nrow = g * 256 + wv * 32 + t * 16 + jj;
            const float* wp = Whh + (size_t)nrow * 256 + hi * 8;
#pragma unroll
            for (int sk = 0; sk < 8; ++sk) {
                float4 w0 = *(const float4*)(wp + sk * 32);
                float4 w1 = *(const float4*)(wp + sk * 32 + 4);
                s16x8 v;
                v[0] = f2bf(w0.x); v[1] = f2bf(w0.y); v[2] = f2bf(w0.z); v[3] = f2bf(w0.w);
                v[4] = f2bf(w1.x); v[5] = f2bf(w1.y); v[6] = f2bf(w1.z); v[7] = f2bf(w1.w);
                wf[g][t][sk] = v;
            }
        }

    const int j0 = wv * 32 + jj, j1 = j0 + 16;
    const float br0 = bhh[j0], bz0 = bhh[256 + j0], bn0 = bhh[512 + j0];
    const float br1 = bhh[j1], bz1 = bhh[256 + j1], bn1 = bhh[512 + j1];

    const int arow = jj >> 2;
    const int abase = arow * HSTRIDE + hi * 16;
    const int wo0 = b * HSTRIDE + 2 * j0;
    const int wo1 = b * HSTRIDE + 2 * j1;

    const int s0 = (dir == 1) ? (L - 1) : 0;
    const int sst = (dir == 1) ? -1 : 1;
    const float* xq = xw + ((size_t)b * L + s0) * D3 + j0;
    float* op;
    int ostride;
    if (dir == 2) { op = dec_out + ((size_t)b * TT + s0) * DIM + j0; ostride = sst * DIM; }
    else          { op = enc_out + ((size_t)b * SS + s0) * D2 + (dir == 1 ? DIM : 0) + j0; ostride = sst * D2; }
    const int xstride = sst * D3;

    float c0 = xq[0], c1 = xq[256], c2 = xq[512], c3 = xq[16], c4 = xq[272], c5 = xq[528];

    float h0 = 0.f, h1 = 0.f;
    int cur = 0;
    __syncthreads();

    for (int st = 0; st < L; ++st) {
        xq += xstride;
        float n0 = xq[0], n1 = xq[256], n2 = xq[512], n3 = xq[16], n4 = xq[272], n5 = xq[528];

        const char* hcur = hb + cur * HBUF;
        f32x4 a00 = {0.f, 0.f, 0.f, 0.f}, a01 = a00, a10 = a00, a11 = a00, a20 = a00, a21 = a00;
#pragma unroll
        for (int sk = 0; sk < 8; ++sk) {
            s16x8 af = *(const s16x8*)(hcur + abase + 64 * sk);
            a00 = __builtin_amdgcn_mfma_f32_16x16x32_bf16(af, wf[0][0][sk], a00, 0, 0, 0);
            a01 = __builtin_amdgcn_mfma_f32_16x16x32_bf16(af, wf[0][1][sk], a01, 0, 0, 0);
            a10 = __builtin_amdgcn_mfma_f32_16x16x32_bf16(af, wf[1][0][sk], a10, 0, 0, 0);
            a11 = __builtin_amdgcn_mfma_f32_16x16x32_bf16(af, wf[1][1][sk], a11, 0, 0, 0);
            a20 = __builtin_amdgcn_mfma_f32_16x16x32_bf16(af, wf[2][0][sk], a20, 0, 0, 0);
            a21 = __builtin_amdgcn_mfma_f32_16x16x32_bf16(af, wf[2][1][sk], a21, 0, 0, 0);
        }

        float r0 = sigmoid_p(c0 + a00[0] + br0);
        float z0 = sigmoid_p(c1 + a10[0] + bz0);
        float nn0 = tanh_p(c2 + r0 * (a20[0] + bn0));
        h0 = (1.f - z0) * nn0 + z0 * h0;
        float r1 = sigmoid_p(c3 + a01[0] + br1);
        float z1 = sigmoid_p(c4 + a11[0] + bz1);
        float nn1 = tanh_p(c5 + r1 * (a21[0] + bn1));
        h1 = (1.f - z1) * nn1 + z1 * h1;

        char* hnxt = hb + (cur ^ 1) * HBUF;
        *(short*)(hnxt + wo0) = f2bf(h0);
        *(short*)(hnxt + wo1) = f2bf(h1);
        op[0] = h0;
        op[16] = h1;
        BAR_LGKM();

        cur ^= 1;
        c0 = n0; c1 = n1; c2 = n2; c3 = n3; c4 = n4; c5 = n5;
        op += ostride;
    }
}

// ---------------------------------------------------------------------------
// Attention, TB=4 t-rows per block (512 threads): Kb row and enc_out reads
// amortized 4x (1.5GB -> 380MB of L2 traffic).
// ---------------------------------------------------------------------------
#define TBR 4
__global__ __launch_bounds__(512) void k_attn(const float* __restrict__ Qb,
                                              const float* __restrict__ Kb,
                                              const float* __restrict__ enc_out,
                                              const float* __restrict__ dec_out,
                                              const float* __restrict__ Wgate,
                                              const float* __restrict__ bgate,
                                              float* __restrict__ probs,
                                              short* __restrict__ cmb,
                                              float* __restrict__ gate) {
    __shared__ float q[TBR][DIM];          // 4 KB
    __shared__ float sc[TBR][SS];          // 8 KB
    __shared__ float red[512];             // 2 KB
    __shared__ float par[2][2][TBR][DIM];  // 16 KB
    __shared__ float gred[TBR][DIM];       // 4 KB
    int row0 = blockIdx.x * TBR;
    int b = row0 >> 8;
    int tid = threadIdx.x;

    // load Q (4 rows)
#pragma unroll
    for (int p = 0; p < 2; ++p) {
        int idx = tid + p * 512;
        q[idx >> 8][idx & 255] = Qb[(size_t)(row0 + (idx >> 8)) * DIM + (idx & 255)];
    }
    __syncthreads();

    const float scale = 0.0625f;  // 1/sqrt(256)
    {   // scores: thread owns s = tid, computes all 4 rows (K row read once)
        const float* kr = Kb + ((size_t)b * SS + tid) * DIM;
        float a0 = 0.f, a1 = 0.f, a2 = 0.f, a3 = 0.f;
        for (int k = 0; k < DIM; k += 4) {
            float4 k4 = *(const float4*)&kr[k];
            a0 += k4.x * q[0][k] + k4.y * q[0][k + 1] + k4.z * q[0][k + 2] + k4.w * q[0][k + 3];
            a1 += k4.x * q[1][k] + k4.y * q[1][k + 1] + k4.z * q[1][k + 2] + k4.w * q[1][k + 3];
            a2 += k4.x * q[2][k] + k4.y * q[2][k + 1] + k4.z * q[2][k + 2] + k4.w * q[2][k + 3];
            a3 += k4.x * q[3][k] + k4.y * q[3][k + 1] + k4.z * q[3][k + 2] + k4.w * q[3][k + 3];
        }
        sc[0][tid] = a0 * scale; sc[1][tid] = a1 * scale;
        sc[2][tid] = a2 * scale; sc[3][tid] = a3 * scale;
    }
    __syncthreads();

    // softmax: 128 threads per row
    const int rr = tid >> 7, ri = tid & 127;
    red[tid] = fmaxf(fmaxf(sc[rr][ri], sc[rr][ri + 128]),
                     fmaxf(sc[rr][ri + 256], sc[rr][ri + 384]));
    __syncthreads();
    for (int o = 64; o > 0; o >>= 1) {
        if (ri < o) red[tid] = fmaxf(red[tid], red[tid + o]);
        __syncthreads();
    }
    float m = red[rr << 7];
    __syncthreads();

    float e0 = __expf(sc[rr][ri] - m);
    float e1 = __expf(sc[rr][ri + 128] - m);
    float e2 = __expf(sc[rr][ri + 256] - m);
    float e3 = __expf(sc[rr][ri + 384] - m);
    sc[rr][ri] = e0; sc[rr][ri + 128] = e1; sc[rr][ri + 256] = e2; sc[rr][ri + 384] = e3;
    red[tid] = e0 + e1 + e2 + e3;
    __syncthreads();
    for (int o = 64; o > 0; o >>= 1) {
        if (ri < o) red[tid] += red[tid + o];
        __syncthreads();
    }
    float inv = rcp_(red[rr << 7]);
    __syncthreads();
    sc[rr][ri] *= inv; sc[rr][ri + 128] *= inv;
    sc[rr][ri + 256] *= inv; sc[rr][ri + 384] *= inv;
    __syncthreads();

    // write probs (4 rows x 512)
#pragma unroll
    for (int p = 0; p < 4; ++p) {
        int idx = tid + p * 512;
        probs[(size_t)(row0 + (idx >> 9)) * SS + (idx & 511)] = sc[idx >> 9][idx & 511];
    }

    // context: d = tid&255, sh = tid>>8; enc_out row read once for 4 rows
    {
        int d = tid & 255, sh = tid >> 8;
        float f0 = 0.f, f1 = 0.f, f2 = 0.f, f3 = 0.f;
        float g0 = 0.f, g1 = 0.f, g2 = 0.f, g3 = 0.f;
        const float* ep = enc_out + ((size_t)b * SS + sh * 256) * D2 + d;
        for (int s = 0; s < 256; ++s) {
            float ef_ = ep[(size_t)s * D2];
            float eb_ = ep[(size_t)s * D2 + DIM];
            int s2 = sh * 256 + s;
            float p0 = sc[0][s2], p1 = sc[1][s2], p2 = sc[2][s2], p3 = sc[3][s2];
            f0 += p0 * ef_; f1 += p1 * ef_; f2 += p2 * ef_; f3 += p3 * ef_;
            g0 += p0 * eb_; g1 += p1 * eb_; g2 += p2 * eb_; g3 += p3 * eb_;
        }
        par[sh][0][0][d] = f0; par[sh][0][1][d] = f1; par[sh][0][2][d] = f2; par[sh][0][3][d] = f3;
        par[sh][1][0][d] = g0; par[sh][1][1][d] = g1; par[sh][1][2][d] = g2; par[sh][1][3][d] = g3;
    }
    __syncthreads();

    // combine + cmb writes + gate partials
    if (tid < DIM) {
        float w0 = Wgate[tid], w1 = Wgate[DIM + tid], w2 = Wgate[2 * DIM + tid];
#pragma unroll
        for (int r = 0; r < TBR; ++r) {
            float af = par[0][0][r][tid] + par[1][0][r][tid];
            float ab = par[0][1][r][tid] + par[1][1][r][tid];
            float dv = dec_out[(size_t)(row0 + r) * DIM + tid];
            size_t cb = (size_t)(row0 + r) * D3;
            cmb[cb + tid] = f2bf(dv);
            cmb[cb + DIM + tid] = f2bf(af);
            cmb[cb + 2 * DIM + tid] = f2bf(ab);
            gred[r][tid] = dv * w0 + af * w1 + ab * w2;
        }
    }
    __syncthreads();

    // 4 parallel gate reductions over 256 (128 threads per row)
    red[tid] = gred[rr][ri] + gred[rr][ri + 128];
    __syncthreads();
    for (int o = 64; o > 0; o >>= 1) {
        if (ri < o) red[tid] += red[tid + o];
        __syncthreads();
    }
    if (ri == 0) gate[row0 + rr] = sigmoidf_(red[rr << 7] + bgate[0]);
}

// ---------------------------------------------------------------------------
// Generator GEMM, 2-phase double-buffered: next-tile loads issued BEFORE the
// current tile's MFMAs (latency hides under compute); ONE barrier per K-iter.
// The old form issued loads then immediately barriered -> vmcnt(0) drain
// exposed full load latency every iteration.
// ---------------------------------------------------------------------------
#define GEN_PROLOGUE()                                                      \
    __shared__ __align__(16) short As[2][256 * 32];                         \
    __shared__ __align__(16) short Bs[2][128 * 32];                         \
    int tid = threadIdx.x;                                                  \
    int lane = tid & 63, wv = tid >> 6;                                     \
    int wm = wv >> 1, wn = wv & 1;                                          \
    int brow = blockIdx.y * 256, bcol = blockIdx.x * 128;                   \
    f32x4 acc[4][4];                                                        \
    _Pragma("unroll") for (int i = 0; i < 4; i++)                           \
        _Pragma("unroll") for (int j = 0; j < 4; j++)                       \
            acc[i][j] = (f32x4){0.f, 0.f, 0.f, 0.f};                        \
    const int ca0 = tid, ca1 = tid + 512, cb = tid;                         \
    const int ll = lane & 15, lh = lane >> 4;

#define LOADA(k)                                                            \
    va0 = *(const s16x8*)&A[(size_t)(brow + (ca0 >> 2)) * D3 + (k) + (ca0 & 3) * 8]; \
    va1 = *(const s16x8*)&A[(size_t)(brow + (ca1 >> 2)) * D3 + (k) + (ca1 & 3) * 8];

#define LOADB_BF(k)                                                         \
    vb = *(const s16x8*)&Bbf[(size_t)(bcol + (cb >> 2)) * D3 + (k) + (cb & 3) * 8]

#define LOADB_F32(k) do {                                                   \
        const float* bp = &Bw[(size_t)(bcol + (cb >> 2)) * D3 + (k) + (cb & 3) * 8]; \
        float4 b0 = *(const float4*)bp; float4 b1 = *(const float4*)(bp + 4); \
        vb[0] = f2bf(b0.x); vb[1] = f2bf(b0.y); vb[2] = f2bf(b0.z); vb[3] = f2bf(b0.w); \
        vb[4] = f2bf(b1.x); vb[5] = f2bf(b1.y); vb[6] = f2bf(b1.z); vb[7] = f2bf(b1.w); } while (0)

#define GEN_MAIN2(LOADB)                                                    \
    {                                                                       \
        s16x8 va0, va1, vb;                                                 \
        LOADA(0); LOADB(0);                                                 \
        *(s16x8*)&As[0][ca0 * 8] = va0;                                     \
        *(s16x8*)&As[0][ca1 * 8] = va1;                                     \
        *(s16x8*)&Bs[0][cb * 8] = vb;                                       \
        __syncthreads();                                                    \
    }                                                                       \
    for (int k0 = 0; k0 < D3; k0 += 32) {                                   \
        const int cur = (k0 >> 5) & 1;                                      \
        const int kn = k0 + 32;                                             \
        s16x8 va0, va1, vb;                                                 \
        if (kn < D3) { LOADA(kn); LOADB(kn); }                              \
        s16x8 af[4], bf[4];                                                 \
        _Pragma("unroll") for (int mt = 0; mt < 4; ++mt)                    \
            af[mt] = *(const s16x8*)&As[cur][(wm * 64 + mt * 16 + ll) * 32 + lh * 8]; \
        _Pragma("unroll") for (int nt = 0; nt < 4; ++nt)                    \
            bf[nt] = *(const s16x8*)&Bs[cur][(wn * 64 + nt * 16 + ll) * 32 + lh * 8]; \
        _Pragma("unroll") for (int mt = 0; mt < 4; ++mt)                    \
            _Pragma("unroll") for (int nt = 0; nt < 4; ++nt)                \
                acc[mt][nt] = __builtin_amdgcn_mfma_f32_16x16x32_bf16(af[mt], bf[nt], acc[mt][nt], 0, 0, 0); \
        if (kn < D3) {                                                      \
            *(s16x8*)&As[cur ^ 1][ca0 * 8] = va0;                           \
            *(s16x8*)&As[cur ^ 1][ca1 * 8] = va1;                           \
            *(s16x8*)&Bs[cur ^ 1][cb * 8] = vb;                             \
        }                                                                   \
        __syncthreads();                                                    \
    }

#define GEN_ROWSUM(EXPR)                                                    \
    _Pragma("unroll") for (int mt = 0; mt < 4; ++mt)                        \
        _Pragma("unroll") for (int q = 0; q < 4; ++q) {                     \
            float se = (EXPR);                                              \
            _Pragma("unroll") for (int off = 1; off < 16; off <<= 1)        \
                se += __shfl_xor(se, off);                                  \
            if (ll == 0) atomicAdd(&rowsum[brow + wm * 64 + mt * 16 + lh * 4 + q], se); \
        }

// bf16-B, bf16 logits out (primary path)
__global__ __launch_bounds__(512) void k_genb(const short* __restrict__ A,
                                              const short* __restrict__ Bbf,
                                              const float* __restrict__ bias,
                                              short* __restrict__ C16,
                                              float* __restrict__ rowsum) {
    GEN_PROLOGUE();
    GEN_MAIN2(LOADB_BF);
    short lr[4][4][4];
#pragma unroll
    for (int nt = 0; nt < 4; ++nt) {
        float bv = bias[bcol + wn * 64 + nt * 16 + ll];
#pragma unroll
        for (int mt = 0; mt < 4; ++mt)
#pragma unroll
            for (int q = 0; q < 4; ++q) lr[mt][nt][q] = f2bf(acc[mt][nt][q] + bv);
    }
#pragma unroll
    for (int mt = 0; mt < 4; ++mt) {
        int row = brow + wm * 64 + mt * 16 + lh * 4;
#pragma unroll
        for (int nt = 0; nt < 4; ++nt) {
            int col = bcol + wn * 64 + nt * 16 + ll;
#pragma unroll
            for (int q = 0; q < 4; ++q)
                C16[(size_t)(row + q) * VV + col] = lr[mt][nt][q];
        }
    }
    GEN_ROWSUM(__expf(bf2f(lr[mt][0][q])) + __expf(bf2f(lr[mt][1][q])) +
               __expf(bf2f(lr[mt][2][q])) + __expf(bf2f(lr[mt][3][q])));
}

// bf16-B, f32 logits out (fallback)
__global__ __launch_bounds__(512) void k_gen_bf(const short* __restrict__ A,
                                                const short* __restrict__ Bbf,
                                                const float* __restrict__ bias,
                                                float* __restrict__ C,
                                                float* __restrict__ rowsum) {
    GEN_PROLOGUE();
    GEN_MAIN2(LOADB_BF);
#pragma unroll
    for (int nt = 0; nt < 4; ++nt) {
        float bv = bias[bcol + wn * 64 + nt * 16 + ll];
#pragma unroll
        for (int mt = 0; mt < 4; ++mt)
#pragma unroll
            for (int q = 0; q < 4; ++q) acc[mt][nt][q] += bv;
    }
#pragma unroll
    for (int mt = 0; mt < 4; ++mt) {
        int row = brow + wm * 64 + mt * 16 + lh * 4;
#pragma unroll
        for (int nt = 0; nt < 4; ++nt) {
            int col = bcol + wn * 64 + nt * 16 + ll;
#pragma unroll
            for (int q = 0; q < 4; ++q)
                C[(size_t)(row + q) * VV + col] = acc[mt][nt][q];
        }
    }
    GEN_ROWSUM(__expf(acc[mt][0][q]) + __expf(acc[mt][1][q]) +
               __expf(acc[mt][2][q]) + __expf(acc[mt][3][q]));
}

// f32-B, f32 logits out (fallback)
__global__ __launch_bounds__(512) void k_gen(const short* __restrict__ A,
                                             const float* __restrict__ Bw,
                                             const float* __restrict__ bias,
                                             float* __restrict__ C,
                                             float* __restrict__ rowsum) {
    GEN_PROLOGUE();
    GEN_MAIN2(LOADB_F32);
#pragma unroll
    for (int nt = 0; nt < 4; ++nt) {
        float bv = bias[bcol + wn * 64 + nt * 16 + ll];
#pragma unroll
        for (int mt = 0; mt < 4; ++mt)
#pragma unroll
            for (int q = 0; q < 4; ++q) acc[mt][nt][q] += bv;
    }
#pragma unroll
    for (int mt = 0; mt < 4; ++mt) {
        int row = brow + wm * 64 + mt * 16 + lh * 4;
#pragma unroll
        for (int nt = 0; nt < 4; ++nt) {
            int col = bcol + wn * 64 + nt * 16 + ll;
#pragma unroll
            for (int q = 0; q < 4; ++q)
                C[(size_t)(row + q) * VV + col] = acc[mt][nt][q];
        }
    }
    GEN_ROWSUM(__expf(acc[mt][0][q]) + __expf(acc[mt][1][q]) +
               __expf(acc[mt][2][q]) + __expf(acc[mt][3][q]));
}

// ---------------------------------------------------------------------------
// Fused normalize + copy-scatter, bf16-logit variant.
// ---------------------------------------------------------------------------
__global__ __launch_bounds__(256) void k_finsc_bf(const int* __restrict__ src,
                                                  const float* __restrict__ probs,
                                                  const float* __restrict__ gate,
                                                  const float* __restrict__ rowsum,
                                                  const short* __restrict__ L16,
                                                  float* __restrict__ out) {
    int row = blockIdx.x;
    int b = row >> 8;
    int tid = threadIdx.x;
    float g = gate[row];
    float inv = g / rowsum[row];
    const short* lp = L16 + (size_t)row * VV;
    float* op = out + (size_t)row * VV;

    for (int i = tid; i < VV / 8; i += 256) {
        s16x8 l8 = *(const s16x8*)&lp[i * 8];
        float4 o0, o1;
        o0.x = __expf(bf2f(l8[0])) * inv; o0.y = __expf(bf2f(l8[1])) * inv;
        o0.z = __expf(bf2f(l8[2])) * inv; o0.w = __expf(bf2f(l8[3])) * inv;
        o1.x = __expf(bf2f(l8[4])) * inv; o1.y = __expf(bf2f(l8[5])) * inv;
        o1.z = __expf(bf2f(l8[6])) * inv; o1.w = __expf(bf2f(l8[7])) * inv;
        *(float4*)&op[i * 8] = o0;
        *(float4*)&op[i * 8 + 4] = o1;
    }
    __syncthreads();

    float og = 1.0f - g;
#pragma unroll
    for (int h = 0; h < 2; ++h) {
        int s = tid + h * 256;
        float val = og * probs[(size_t)row * SS + s];
        atomicAdd(&op[src[b * SS + s]], val);
    }
}

// f32-logit variant
__global__ __launch_bounds__(256) void k_finsc(const int* __restrict__ src,
                                               const float* __restrict__ probs,
                                               const float* __restrict__ gate,
                                               const float* __restrict__ rowsum,
                                               float* __restrict__ out) {
    int row = blockIdx.x;
    int b = row >> 8;
    int tid = threadIdx.x;
    float g = gate[row];
    float inv = g / rowsum[row];
    float* op = out + (size_t)row * VV;

    for (int i = tid; i < VV / 4; i += 256) {
        float4 l = *(const float4*)&op[i * 4];
        l.x = __expf(l.x) * inv;
        l.y = __expf(l.y) * inv;
        l.z = __expf(l.z) * inv;
        l.w = __expf(l.w) * inv;
        *(float4*)&op[i * 4] = l;
    }
    __syncthreads();

    float og = 1.0f - g;
#pragma unroll
    for (int h = 0; h < 2; ++h) {
        int s = tid + h * 256;
        float val = og * probs[(size_t)row * SS + s];
        atomicAdd(&op[src[b * SS + s]], val);
    }
}

// ---------------------------------------------------------------------------
extern "C" void kernel_launch(void* const* d_in, const int* in_sizes, int n_in,
                              void* d_out, int out_size, void* d_ws, size_t ws_size,
                              hipStream_t stream) {
    const int*   src    = (const int*)d_in[0];
    const int*   tgt    = (const int*)d_in[1];
    const float* emb    = (const float*)d_in[2];
    const float* pos    = (const float*)d_in[3];
    const float* ef_wih = (const float*)d_in[4];
    const float* ef_whh = (const float*)d_in[5];
    const float* ef_bih = (const float*)d_in[6];
    const float* ef_bhh = (const float*)d_in[7];
    const float* eb_wih = (const float*)d_in[8];
    const float* eb_whh = (const float*)d_in[9];
    const float* eb_bih = (const float*)d_in[10];
    const float* eb_bhh = (const float*)d_in[11];
    const float* d_wih  = (const float*)d_in[12];
    const float* d_whh  = (const float*)d_in[13];
    const float* d_bih  = (const float*)d_in[14];
    const float* d_bhh  = (const float*)d_in[15];
    const float* Wq     = (const float*)d_in[16];
    const float* Wk     = (const float*)d_in[17];
    const float* Wgen   = (const float*)d_in[18];
    const float* bgen   = (const float*)d_in[19];
    const float* Wgate  = (const float*)d_in[20];
    const float* bgate  = (const float*)d_in[21];
    float* out = (float*)d_out;
    float* ws  = (float*)d_ws;

    float* ef_x     = ws;
    float* eb_x     = ef_x + (size_t)BB * SS * D3;
    float* d_x      = eb_x + (size_t)BB * SS * D3;
    float* enc_out  = d_x + (size_t)BB * TT * D3;
    float* dec_out  = enc_out + (size_t)BB * SS * D2;
    float* Qb       = dec_out + (size_t)BB * TT * DIM;
    float* Kb       = Qb + (size_t)BB * TT * DIM;
    float* probs    = Kb + (size_t)BB * SS * DIM;
    short* cmb_bf   = (short*)(probs + (size_t)BB * TT * SS);
    float* gate     = (float*)(cmb_bf + (size_t)BB * TT * D3);
    float* rowsum   = gate + 1024;
    short* wgen_bf  = (short*)(rowsum + 1024);
    short* logit_bf = wgen_bf + (size_t)VV * D3;
    const bool use_bf  = ws_size >= (size_t)((char*)(wgen_bf + (size_t)VV * D3) - (char*)d_ws);
    const bool use_lbf = ws_size >= (size_t)((char*)(logit_bf + (size_t)VV * BB * TT) - (char*)d_ws);

    // 1. input projections with fused embedding (bf16 MFMA)
    {
        PDesc e0 = {src, ef_wih, ef_bih, ef_x, BB * SS, SS - 1};
        PDesc e1 = {src, eb_wih, eb_bih, eb_x, BB * SS, SS - 1};
        PDesc e2 = {tgt, d_wih, d_bih, d_x, BB * TT, TT - 1};
        k_proj<<<dim3(D3 / 128, BB * SS / 256, 3), 512, 0, stream>>>(emb, pos, e0, e1, e2);
    }

    // 2. recurrences + Wgen cvt + rowsum zero on idle CUs
    {
        int ncvtb = (int)((NCVT8 + 511) / 512);
        k_gru<<<3 + ncvtb, 512, 0, stream>>>(ef_x, eb_x, d_x,
                                             ef_whh, ef_bhh, eb_whh, eb_bhh, d_whh, d_bhh,
                                             enc_out, dec_out,
                                             Wgen, wgen_bf, rowsum, use_bf ? 1 : 0);
    }

    // 3. Q/K projections (bf16 MFMA)
    {
        QDesc q0 = {dec_out, DIM, Wq, Qb, BB * TT};
        QDesc q1 = {enc_out, D2, Wk, Kb, BB * SS};
        k_qk<<<dim3(DIM / 128, BB * SS / 256, 2), 512, 0, stream>>>(q0, q1);
    }

    // 4. attention + combined(bf16) + gate (TB=4 rows per block)
    k_attn<<<BB * TT / TBR, 512, 0, stream>>>(Qb, Kb, enc_out, dec_out, Wgate, bgate,
                                              probs, cmb_bf, gate);

    // 5+6. generator logits + rowsum, then normalize + copy-scatter
    dim3 gg(VV / 128, (BB * TT) / 256);
    if (use_lbf) {
        k_genb<<<gg, 512, 0, stream>>>(cmb_bf, wgen_bf, bgen, logit_bf, rowsum);
        k_finsc_bf<<<BB * TT, 256, 0, stream>>>(src, probs, gate, rowsum, logit_bf, out);
    } else if (use_bf) {
        k_gen_bf<<<gg, 512, 0, stream>>>(cmb_bf, wgen_bf, bgen, out, rowsum);
        k_finsc<<<BB * TT, 256, 0, stream>>>(src, probs, gate, rowsum, out);
    } else {
        k_gen<<<gg, 512, 0, stream>>>(cmb_bf, Wgen, bgen, out, rowsum);
        k_finsc<<<BB * TT, 256, 0, stream>>>(src, probs, gate, rowsum, out);
    }
}

// Round 13
// 1071.041 us; speedup vs baseline: 1.0327x; 1.0327x over previous
//
#include <hip/hip_runtime.h>
#include <hip/hip_bf16.h>
#include <math.h>

// Problem dims
#define VV   32000
#define DIM  256
#define BB   4
#define SS   512
#define TT   256
#define D2   512
#define D3   768

typedef __attribute__((ext_vector_type(8))) short s16x8;
typedef __attribute__((ext_vector_type(4))) float f32x4;

__device__ __forceinline__ float rcp_(float x) { return __builtin_amdgcn_rcpf(x); }
__device__ __forceinline__ float sigmoidf_(float x) { return rcp_(1.0f + __expf(-x)); }
// precise forms for the GRU epilogue (R6's 680us config)
__device__ __forceinline__ float sigmoid_p(float x) { return 1.0f / (1.0f + __expf(-x)); }
__device__ __forceinline__ float tanh_p(float x) {
    float e2 = __expf(2.0f * x);
    return (e2 - 1.0f) / (e2 + 1.0f);
}
__device__ __forceinline__ short f2bf(float f) {  // RNE f32->bf16
    unsigned u = __float_as_uint(f);
    u += 0x7FFFu + ((u >> 16) & 1u);
    return (short)(u >> 16);
}
__device__ __forceinline__ float bf2f(short s) {
    return __uint_as_float(((unsigned)(unsigned short)s) << 16);
}

// R4-proven barrier: lgkm-only drain keeps global loads/stores in flight.
#define BAR_LGKM() asm volatile("s_waitcnt lgkmcnt(0)\n\ts_barrier" ::: "memory")

// ---------------------------------------------------------------------------
// Input projections with FUSED embedding: C[M,768] = (emb[tok]+pos) @ W^T + b.
// ---------------------------------------------------------------------------
struct PDesc {
    const int* tok;
    const float* Wt;
    const float* bias;
    float* C;
    int M;
    int lmask;
};

__global__ __launch_bounds__(512) void k_proj(const float* __restrict__ emb,
                                              const float* __restrict__ pos,
                                              PDesc p0, PDesc p1, PDesc p2) {
    PDesc p = (blockIdx.z == 0) ? p0 : ((blockIdx.z == 1) ? p1 : p2);
    int brow = blockIdx.y * 256;
    if (brow >= p.M) return;
    int bcol = blockIdx.x * 128;

    __shared__ __align__(16) short As[256 * 32];
    __shared__ __align__(16) short Bs[128 * 32];
    int tid = threadIdx.x;
    int lane = tid & 63, wv = tid >> 6;
    int wm = wv >> 1, wn = wv & 1;
    const int ll = lane & 15, lh = lane >> 4;

    f32x4 acc[4][4];
#pragma unroll
    for (int i = 0; i < 4; i++)
#pragma unroll
        for (int j = 0; j < 4; j++) acc[i][j] = (f32x4){0.f, 0.f, 0.f, 0.f};

    const int ar = tid >> 1, ak = (tid & 1) * 16;
    const int br = tid >> 2, bk = (tid & 3) * 8;
    const int grow = brow + ar;
    const float* erow = emb + (size_t)p.tok[grow] * DIM;
    const float* prow = pos + (size_t)(grow & p.lmask) * DIM;

    for (int k0 = 0; k0 < DIM; k0 += 32) {
        float4 a0 = *(const float4*)(erow + k0 + ak);
        float4 a1 = *(const float4*)(erow + k0 + ak + 4);
        float4 a2 = *(const float4*)(erow + k0 + ak + 8);
        float4 a3 = *(const float4*)(erow + k0 + ak + 12);
        float4 q0 = *(const float4*)(prow + k0 + ak);
        float4 q1 = *(const float4*)(prow + k0 + ak + 4);
        float4 q2 = *(const float4*)(prow + k0 + ak + 8);
        float4 q3 = *(const float4*)(prow + k0 + ak + 12);
        const float* bp = &p.Wt[(size_t)(bcol + br) * DIM + k0 + bk];
        float4 b0 = *(const float4*)bp;
        float4 b1 = *(const float4*)(bp + 4);
        s16x8 va0, va1, vb;
        va0[0] = f2bf(a0.x + q0.x); va0[1] = f2bf(a0.y + q0.y);
        va0[2] = f2bf(a0.z + q0.z); va0[3] = f2bf(a0.w + q0.w);
        va0[4] = f2bf(a1.x + q1.x); va0[5] = f2bf(a1.y + q1.y);
        va0[6] = f2bf(a1.z + q1.z); va0[7] = f2bf(a1.w + q1.w);
        va1[0] = f2bf(a2.x + q2.x); va1[1] = f2bf(a2.y + q2.y);
        va1[2] = f2bf(a2.z + q2.z); va1[3] = f2bf(a2.w + q2.w);
        va1[4] = f2bf(a3.x + q3.x); va1[5] = f2bf(a3.y + q3.y);
        va1[6] = f2bf(a3.z + q3.z); va1[7] = f2bf(a3.w + q3.w);
        vb[0] = f2bf(b0.x); vb[1] = f2bf(b0.y); vb[2] = f2bf(b0.z); vb[3] = f2bf(b0.w);
        vb[4] = f2bf(b1.x); vb[5] = f2bf(b1.y); vb[6] = f2bf(b1.z); vb[7] = f2bf(b1.w);

        __syncthreads();
        *(s16x8*)&As[ar * 32 + ak] = va0;
        *(s16x8*)&As[ar * 32 + ak + 8] = va1;
        *(s16x8*)&Bs[br * 32 + bk] = vb;
        __syncthreads();

        s16x8 af[4], bf[4];
#pragma unroll
        for (int mt = 0; mt < 4; ++mt)
            af[mt] = *(const s16x8*)&As[(wm * 64 + mt * 16 + ll) * 32 + lh * 8];
#pragma unroll
        for (int nt = 0; nt < 4; ++nt)
            bf[nt] = *(const s16x8*)&Bs[(wn * 64 + nt * 16 + ll) * 32 + lh * 8];
#pragma unroll
        for (int mt = 0; mt < 4; ++mt)
#pragma unroll
            for (int nt = 0; nt < 4; ++nt)
                acc[mt][nt] = __builtin_amdgcn_mfma_f32_16x16x32_bf16(af[mt], bf[nt], acc[mt][nt], 0, 0, 0);
    }

#pragma unroll
    for (int mt = 0; mt < 4; ++mt) {
        int row = brow + wm * 64 + mt * 16 + lh * 4;
#pragma unroll
        for (int nt = 0; nt < 4; ++nt) {
            int col = bcol + wn * 64 + nt * 16 + ll;
            float bv = p.bias[col];
#pragma unroll
            for (int q = 0; q < 4; ++q)
                p.C[(size_t)(row + q) * D3 + col] = acc[mt][nt][q] + bv;
        }
    }
}

// ---------------------------------------------------------------------------
// Q/K projections as bf16 MFMA.
// ---------------------------------------------------------------------------
struct QDesc {
    const float* A; int K;
    const float* Bt;
    float* C;
    int M;
};

__global__ __launch_bounds__(512) void k_qk(QDesc q0d, QDesc q1d) {
    QDesc p = (blockIdx.z == 0) ? q0d : q1d;
    int brow = blockIdx.y * 256;
    if (brow >= p.M) return;
    int bcol = blockIdx.x * 128;
    const int K = p.K;

    __shared__ __align__(16) short As[256 * 32];
    __shared__ __align__(16) short Bs[128 * 32];
    int tid = threadIdx.x;
    int lane = tid & 63, wv = tid >> 6;
    int wm = wv >> 1, wn = wv & 1;
    const int ll = lane & 15, lh = lane >> 4;

    f32x4 acc[4][4];
#pragma unroll
    for (int i = 0; i < 4; i++)
#pragma unroll
        for (int j = 0; j < 4; j++) acc[i][j] = (f32x4){0.f, 0.f, 0.f, 0.f};

    const int ar = tid >> 1, ak = (tid & 1) * 16;
    const int br = tid >> 2, bk = (tid & 3) * 8;

    for (int k0 = 0; k0 < K; k0 += 32) {
        const float* ap = &p.A[(size_t)(brow + ar) * K + k0 + ak];
        float4 a0 = *(const float4*)ap;
        float4 a1 = *(const float4*)(ap + 4);
        float4 a2 = *(const float4*)(ap + 8);
        float4 a3 = *(const float4*)(ap + 12);
        const float* bp = &p.Bt[(size_t)(bcol + br) * K + k0 + bk];
        float4 b0 = *(const float4*)bp;
        float4 b1 = *(const float4*)(bp + 4);
        s16x8 va0, va1, vb;
        va0[0] = f2bf(a0.x); va0[1] = f2bf(a0.y); va0[2] = f2bf(a0.z); va0[3] = f2bf(a0.w);
        va0[4] = f2bf(a1.x); va0[5] = f2bf(a1.y); va0[6] = f2bf(a1.z); va0[7] = f2bf(a1.w);
        va1[0] = f2bf(a2.x); va1[1] = f2bf(a2.y); va1[2] = f2bf(a2.z); va1[3] = f2bf(a2.w);
        va1[4] = f2bf(a3.x); va1[5] = f2bf(a3.y); va1[6] = f2bf(a3.z); va1[7] = f2bf(a3.w);
        vb[0] = f2bf(b0.x); vb[1] = f2bf(b0.y); vb[2] = f2bf(b0.z); vb[3] = f2bf(b0.w);
        vb[4] = f2bf(b1.x); vb[5] = f2bf(b1.y); vb[6] = f2bf(b1.z); vb[7] = f2bf(b1.w);

        __syncthreads();
        *(s16x8*)&As[ar * 32 + ak] = va0;
        *(s16x8*)&As[ar * 32 + ak + 8] = va1;
        *(s16x8*)&Bs[br * 32 + bk] = vb;
        __syncthreads();

        s16x8 af[4], bf[4];
#pragma unroll
        for (int mt = 0; mt < 4; ++mt)
            af[mt] = *(const s16x8*)&As[(wm * 64 + mt * 16 + ll) * 32 + lh * 8];
#pragma unroll
        for (int nt = 0; nt < 4; ++nt)
            bf[nt] = *(const s16x8*)&Bs[(wn * 64 + nt * 16 + ll) * 32 + lh * 8];
#pragma unroll
        for (int mt = 0; mt < 4; ++mt)
#pragma unroll
            for (int nt = 0; nt < 4; ++nt)
                acc[mt][nt] = __builtin_amdgcn_mfma_f32_16x16x32_bf16(af[mt], bf[nt], acc[mt][nt], 0, 0, 0);
    }

#pragma unroll
    for (int mt = 0; mt < 4; ++mt) {
        int row = brow + wm * 64 + mt * 16 + lh * 4;
#pragma unroll
        for (int nt = 0; nt < 4; ++nt) {
            int col = bcol + wn * 64 + nt * 16 + ll;
#pragma unroll
            for (int q = 0; q < 4; ++q)
                p.C[(size_t)(row + q) * DIM + col] = acc[mt][nt][q];
        }
    }
}

// ---------------------------------------------------------------------------
// GRU recurrences (R6-exact 680us form) + fused Wgen cvt / rowsum zeroing.
// DYNAMIC LDS = 88KB forces 1 block/CU: cvt side-blocks can no longer be
// co-scheduled onto the 3 recurrence CUs (R11/R12 counters showed VALUBusy
// 0.44->0.70 and dur 680->707-730 from that contention).
// ---------------------------------------------------------------------------
#define HSTRIDE 576
#define HBUF    (4 * HSTRIDE)
#define NCVT8   ((size_t)VV * D3 / 8)
#define GRU_LDS 90112   // 88KB -> max 1 block/CU (160KB budget)

__global__ __launch_bounds__(512, 1) void k_gru(const float* __restrict__ ef_x,
                                                const float* __restrict__ eb_x,
                                                const float* __restrict__ d_x,
                                                const float* __restrict__ ef_whh, const float* __restrict__ ef_bhh,
                                                const float* __restrict__ eb_whh, const float* __restrict__ eb_bhh,
                                                const float* __restrict__ d_whh, const float* __restrict__ d_bhh,
                                                float* __restrict__ enc_out,
                                                float* __restrict__ dec_out,
                                                const float* __restrict__ wgen,
                                                short* __restrict__ wgen_bf,
                                                float* __restrict__ rowsum,
                                                int do_cvt) {
    extern __shared__ __align__(16) char hb[];   // 2*HBUF used; 88KB reserved
    int tid = threadIdx.x;
    int bid = blockIdx.x;

    if (bid >= 3) {   // fused side-work, now on CUs exclusive of the recurrence
        int cb = bid - 3;
        if (cb == 0) { rowsum[tid] = 0.0f; rowsum[tid + 512] = 0.0f; }
        if (do_cvt) {
            size_t i = (size_t)cb * 512 + tid;
            if (i < NCVT8) {
                const float4* p = (const float4*)(wgen + i * 8);
                float4 a = p[0], b4 = p[1];
                s16x8 v;
                v[0] = f2bf(a.x); v[1] = f2bf(a.y); v[2] = f2bf(a.z); v[3] = f2bf(a.w);
                v[4] = f2bf(b4.x); v[5] = f2bf(b4.y); v[6] = f2bf(b4.z); v[7] = f2bf(b4.w);
                *(s16x8*)(wgen_bf + i * 8) = v;
            }
        }
        return;
    }

    int dir = bid;
    const float *xw, *Whh, *bhh;
    int L;
    if (dir == 0)      { xw = ef_x; Whh = ef_whh; bhh = ef_bhh; L = SS; }
    else if (dir == 1) { xw = eb_x; Whh = eb_whh; bhh = eb_bhh; L = SS; }
    else               { xw = d_x;  Whh = d_whh;  bhh = d_bhh;  L = TT; }

    const int wv = tid >> 6;
    const int lane = tid & 63;
    const int jj = lane & 15;
    const int hi = lane >> 4;
    const int b = hi;

    if (tid < 288) {
        f32x4 z = {0.f, 0.f, 0.f, 0.f};
        *(f32x4*)(hb + tid * 16) = z;
    }

    s16x8 wf[3][2][8];
#pragma unroll
    for (int g = 0; g < 3; ++g)
#pragma unroll
        for (int t = 0; t < 2; ++t) {
            const int nrow = g * 256 + wv * 32 + t * 16 + jj;
            const float* wp = Whh + (size_t)nrow * 256 + hi * 8;
#pragma unroll
            for (int sk = 0; sk < 8; ++sk) {
                float4 w0 = *(const float4*)(wp + sk * 32);
                float4 w1 = *(const float4*)(wp + sk * 32 + 4);
                s16x8 v;
                v[0] = f2bf(w0.x); v[1] = f2bf(w0.y); v[2] = f2bf(w0.z); v[3] = f2bf(w0.w);
                v[4] = f2bf(w1.x); v[5] = f2bf(w1.y); v[6] = f2bf(w1.z); v[7] = f2bf(w1.w);
                wf[g][t][sk] = v;
            }
        }

    const int j0 = wv * 32 + jj, j1 = j0 + 16;
    const float br0 = bhh[j0], bz0 = bhh[256 + j0], bn0 = bhh[512 + j0];
    const float br1 = bhh[j1], bz1 = bhh[256 + j1], bn1 = bhh[512 + j1];

    const int arow = jj >> 2;
    const int abase = arow * HSTRIDE + hi * 16;
    const int wo0 = b * HSTRIDE + 2 * j0;
    const int wo1 = b * HSTRIDE + 2 * j1;

    const int s0 = (dir == 1) ? (L - 1) : 0;
    const int sst = (dir == 1) ? -1 : 1;
    const float* xq = xw + ((size_t)b * L + s0) * D3 + j0;
    float* op;
    int ostride;
    if (dir == 2) { op = dec_out + ((size_t)b * TT + s0) * DIM + j0; ostride = sst * DIM; }
    else          { op = enc_out + ((size_t)b * SS + s0) * D2 + (dir == 1 ? DIM : 0) + j0; ostride = sst * D2; }
    const int xstride = sst * D3;

    float c0 = xq[0], c1 = xq[256], c2 = xq[512], c3 = xq[16], c4 = xq[272], c5 = xq[528];

    float h0 = 0.f, h1 = 0.f;
    int cur = 0;
    __syncthreads();

    for (int st = 0; st < L; ++st) {
        xq += xstride;
        float n0 = xq[0], n1 = xq[256], n2 = xq[512], n3 = xq[16], n4 = xq[272], n5 = xq[528];

        const char* hcur = hb + cur * HBUF;
        f32x4 a00 = {0.f, 0.f, 0.f, 0.f}, a01 = a00, a10 = a00, a11 = a00, a20 = a00, a21 = a00;
#pragma unroll
        for (int sk = 0; sk < 8; ++sk) {
            s16x8 af = *(const s16x8*)(hcur + abase + 64 * sk);
            a00 = __builtin_amdgcn_mfma_f32_16x16x32_bf16(af, wf[0][0][sk], a00, 0, 0, 0);
            a01 = __builtin_amdgcn_mfma_f32_16x16x32_bf16(af, wf[0][1][sk], a01, 0, 0, 0);
            a10 = __builtin_amdgcn_mfma_f32_16x16x32_bf16(af, wf[1][0][sk], a10, 0, 0, 0);
            a11 = __builtin_amdgcn_mfma_f32_16x16x32_bf16(af, wf[1][1][sk], a11, 0, 0, 0);
            a20 = __builtin_amdgcn_mfma_f32_16x16x32_bf16(af, wf[2][0][sk], a20, 0, 0, 0);
            a21 = __builtin_amdgcn_mfma_f32_16x16x32_bf16(af, wf[2][1][sk], a21, 0, 0, 0);
        }

        float r0 = sigmoid_p(c0 + a00[0] + br0);
        float z0 = sigmoid_p(c1 + a10[0] + bz0);
        float nn0 = tanh_p(c2 + r0 * (a20[0] + bn0));
        h0 = (1.f - z0) * nn0 + z0 * h0;
        float r1 = sigmoid_p(c3 + a01[0] + br1);
        float z1 = sigmoid_p(c4 + a11[0] + bz1);
        float nn1 = tanh_p(c5 + r1 * (a21[0] + bn1));
        h1 = (1.f - z1) * nn1 + z1 * h1;

        char* hnxt = hb + (cur ^ 1) * HBUF;
        *(short*)(hnxt + wo0) = f2bf(h0);
        *(short*)(hnxt + wo1) = f2bf(h1);
        op[0] = h0;
        op[16] = h1;
        BAR_LGKM();

        cur ^= 1;
        c0 = n0; c1 = n1; c2 = n2; c3 = n3; c4 = n4; c5 = n5;
        op += ostride;
    }
}

// ---------------------------------------------------------------------------
// Attention: one block per (b,t) row, 512 threads (R11 form).
// ---------------------------------------------------------------------------
__global__ __launch_bounds__(512) void k_attn(const float* __restrict__ Qb,
                                              const float* __restrict__ Kb,
                                              const float* __restrict__ enc_out,
                                              const float* __restrict__ dec_out,
                                              const float* __restrict__ Wgate,
                                              const float* __restrict__ bgate,
                                              float* __restrict__ probs,
                                              short* __restrict__ cmb,
                                              float* __restrict__ gate) {
    __shared__ float q[DIM];
    __shared__ float sc[SS];
    __shared__ float red[512];
    __shared__ float par[2][2][DIM];
    int row = blockIdx.x;
    int b = row >> 8;
    int tid = threadIdx.x;

    if (tid < DIM) q[tid] = Qb[(size_t)row * DIM + tid];
    __syncthreads();

    const float scale = 0.0625f;
    {
        const float* kr = Kb + ((size_t)b * SS + tid) * DIM;
        float acc = 0.0f;
        for (int k = 0; k < DIM; k += 4) {
            float4 k4 = *(const float4*)&kr[k];
            acc += k4.x * q[k] + k4.y * q[k + 1] + k4.z * q[k + 2] + k4.w * q[k + 3];
        }
        sc[tid] = acc * scale;
    }
    __syncthreads();

    red[tid] = sc[tid];
    __syncthreads();
    for (int o = 256; o > 0; o >>= 1) {
        if (tid < o) red[tid] = fmaxf(red[tid], red[tid + o]);
        __syncthreads();
    }
    float m = red[0];
    __syncthreads();

    float e0 = __expf(sc[tid] - m);
    sc[tid] = e0;
    red[tid] = e0;
    __syncthreads();
    for (int o = 256; o > 0; o >>= 1) {
        if (tid < o) red[tid] += red[tid + o];
        __syncthreads();
    }
    float inv = rcp_(red[0]);
    __syncthreads();

    sc[tid] *= inv;
    probs[(size_t)row * SS + tid] = sc[tid];
    __syncthreads();

    {
        int d = tid & 255, sh = tid >> 8;
        float accf = 0.0f, accb = 0.0f;
        const float* ep = enc_out + ((size_t)b * SS + sh * 256) * D2 + d;
        const float* pp = &sc[sh * 256];
        for (int s = 0; s < 256; s++) {
            float p = pp[s];
            accf += p * ep[(size_t)s * D2];
            accb += p * ep[(size_t)s * D2 + DIM];
        }
        par[sh][0][d] = accf;
        par[sh][1][d] = accb;
    }
    __syncthreads();

    if (tid < DIM) {
        float af = par[0][0][tid] + par[1][0][tid];
        float ab = par[0][1][tid] + par[1][1][tid];
        float dv = dec_out[(size_t)row * DIM + tid];
        cmb[(size_t)row * D3 + tid] = f2bf(dv);
        cmb[(size_t)row * D3 + DIM + tid] = f2bf(af);
        cmb[(size_t)row * D3 + 2 * DIM + tid] = f2bf(ab);
        red[tid] = dv * Wgate[tid] + af * Wgate[DIM + tid] + ab * Wgate[2 * DIM + tid];
    }
    __syncthreads();
    for (int o = 128; o > 0; o >>= 1) {
        if (tid < o) red[tid] += red[tid + o];
        __syncthreads();
    }
    if (tid == 0) gate[row] = sigmoidf_(red[0] + bgate[0]);
}

// ---------------------------------------------------------------------------
// Generator GEMM core (R11 single-buffer form — R12's dbuf regressed).
// ---------------------------------------------------------------------------
#define GEN_PROLOGUE()                                                      \
    __shared__ __align__(16) short As[256 * 32];                            \
    __shared__ __align__(16) short Bs[128 * 32];                            \
    int tid = threadIdx.x;                                                  \
    int lane = tid & 63, wv = tid >> 6;                                     \
    int wm = wv >> 1, wn = wv & 1;                                          \
    int brow = blockIdx.y * 256, bcol = blockIdx.x * 128;                   \
    f32x4 acc[4][4];                                                        \
    _Pragma("unroll") for (int i = 0; i < 4; i++)                           \
        _Pragma("unroll") for (int j = 0; j < 4; j++)                       \
            acc[i][j] = (f32x4){0.f, 0.f, 0.f, 0.f};                        \
    const int ca0 = tid, ca1 = tid + 512, cb = tid;                         \
    const int ll = lane & 15, lh = lane >> 4;

#define GEN_MAINLOOP(LOAD_B)                                                \
    for (int k0 = 0; k0 < D3; k0 += 32) {                                   \
        s16x8 va0 = *(const s16x8*)&A[(size_t)(brow + (ca0 >> 2)) * D3 + k0 + (ca0 & 3) * 8]; \
        s16x8 va1 = *(const s16x8*)&A[(size_t)(brow + (ca1 >> 2)) * D3 + k0 + (ca1 & 3) * 8]; \
        s16x8 vb; LOAD_B;                                                   \
        __syncthreads();                                                    \
        *(s16x8*)&As[ca0 * 8] = va0;                                        \
        *(s16x8*)&As[ca1 * 8] = va1;                                        \
        *(s16x8*)&Bs[cb * 8] = vb;                                          \
        __syncthreads();                                                    \
        s16x8 af[4], bf[4];                                                 \
        _Pragma("unroll") for (int mt = 0; mt < 4; ++mt)                    \
            af[mt] = *(const s16x8*)&As[(wm * 64 + mt * 16 + ll) * 32 + lh * 8]; \
        _Pragma("unroll") for (int nt = 0; nt < 4; ++nt)                    \
            bf[nt] = *(const s16x8*)&Bs[(wn * 64 + nt * 16 + ll) * 32 + lh * 8]; \
        _Pragma("unroll") for (int mt = 0; mt < 4; ++mt)                    \
            _Pragma("unroll") for (int nt = 0; nt < 4; ++nt)                \
                acc[mt][nt] = __builtin_amdgcn_mfma_f32_16x16x32_bf16(af[mt], bf[nt], acc[mt][nt], 0, 0, 0); \
    }

#define LOADB_BF  vb = *(const s16x8*)&Bbf[(size_t)(bcol + (cb >> 2)) * D3 + k0 + (cb & 3) * 8]
#define LOADB_F32 do {                                                      \
        const float* bp = &Bw[(size_t)(bcol + (cb >> 2)) * D3 + k0 + (cb & 3) * 8]; \
        float4 b0 = *(const float4*)bp; float4 b1 = *(const float4*)(bp + 4); \
        vb[0] = f2bf(b0.x); vb[1] = f2bf(b0.y); vb[2] = f2bf(b0.z); vb[3] = f2bf(b0.w); \
        vb[4] = f2bf(b1.x); vb[5] = f2bf(b1.y); vb[6] = f2bf(b1.z); vb[7] = f2bf(b1.w); } while (0)

#define GEN_ROWSUM(EXPR)                                                    \
    _Pragma("unroll") for (int mt = 0; mt < 4; ++mt)                        \
        _Pragma("unroll") for (int q = 0; q < 4; ++q) {                     \
            float se = (EXPR);                                              \
            _Pragma("unroll") for (int off = 1; off < 16; off <<= 1)        \
                se += __shfl_xor(se, off);                                  \
            if (ll == 0) atomicAdd(&rowsum[brow + wm * 64 + mt * 16 + lh * 4 + q], se); \
        }

// bf16-B, bf16 logits out (primary path)
__global__ __launch_bounds__(512) void k_genb(const short* __restrict__ A,
                                              const short* __restrict__ Bbf,
                                              const float* __restrict__ bias,
                                              short* __restrict__ C16,
                                              float* __restrict__ rowsum) {
    GEN_PROLOGUE();
    GEN_MAINLOOP(LOADB_BF);
    short lr[4][4][4];
#pragma unroll
    for (int nt = 0; nt < 4; ++nt) {
        float bv = bias[bcol + wn * 64 + nt * 16 + ll];
#pragma unroll
        for (int mt = 0; mt < 4; ++mt)
#pragma unroll
            for (int q = 0; q < 4; ++q) lr[mt][nt][q] = f2bf(acc[mt][nt][q] + bv);
    }
#pragma unroll
    for (int mt = 0; mt < 4; ++mt) {
        int row = brow + wm * 64 + mt * 16 + lh * 4;
#pragma unroll
        for (int nt = 0; nt < 4; ++nt) {
            int col = bcol + wn * 64 + nt * 16 + ll;
#pragma unroll
            for (int q = 0; q < 4; ++q)
                C16[(size_t)(row + q) * VV + col] = lr[mt][nt][q];
        }
    }
    GEN_ROWSUM(__expf(bf2f(lr[mt][0][q])) + __expf(bf2f(lr[mt][1][q])) +
               __expf(bf2f(lr[mt][2][q])) + __expf(bf2f(lr[mt][3][q])));
}

// bf16-B, f32 logits out (fallback)
__global__ __launch_bounds__(512) void k_gen_bf(const short* __restrict__ A,
                                                const short* __restrict__ Bbf,
                                                const float* __restrict__ bias,
                                                float* __restrict__ C,
                                                float* __restrict__ rowsum) {
    GEN_PROLOGUE();
    GEN_MAINLOOP(LOADB_BF);
#pragma unroll
    for (int nt = 0; nt < 4; ++nt) {
        float bv = bias[bcol + wn * 64 + nt * 16 + ll];
#pragma unroll
        for (int mt = 0; mt < 4; ++mt)
#pragma unroll
            for (int q = 0; q < 4; ++q) acc[mt][nt][q] += bv;
    }
#pragma unroll
    for (int mt = 0; mt < 4; ++mt) {
        int row = brow + wm * 64 + mt * 16 + lh * 4;
#pragma unroll
        for (int nt = 0; nt < 4; ++nt) {
            int col = bcol + wn * 64 + nt * 16 + ll;
#pragma unroll
            for (int q = 0; q < 4; ++q)
                C[(size_t)(row + q) * VV + col] = acc[mt][nt][q];
        }
    }
    GEN_ROWSUM(__expf(acc[mt][0][q]) + __expf(acc[mt][1][q]) +
               __expf(acc[mt][2][q]) + __expf(acc[mt][3][q]));
}

// f32-B, f32 logits out (fallback)
__global__ __launch_bounds__(512) void k_gen(const short* __restrict__ A,
                                             const float* __restrict__ Bw,
                                             const float* __restrict__ bias,
                                             float* __restrict__ C,
                                             float* __restrict__ rowsum) {
    GEN_PROLOGUE();
    GEN_MAINLOOP(LOADB_F32);
#pragma unroll
    for (int nt = 0; nt < 4; ++nt) {
        float bv = bias[bcol + wn * 64 + nt * 16 + ll];
#pragma unroll
        for (int mt = 0; mt < 4; ++mt)
#pragma unroll
            for (int q = 0; q < 4; ++q) acc[mt][nt][q] += bv;
    }
#pragma unroll
    for (int mt = 0; mt < 4; ++mt) {
        int row = brow + wm * 64 + mt * 16 + lh * 4;
#pragma unroll
        for (int nt = 0; nt < 4; ++nt) {
            int col = bcol + wn * 64 + nt * 16 + ll;
#pragma unroll
            for (int q = 0; q < 4; ++q)
                C[(size_t)(row + q) * VV + col] = acc[mt][nt][q];
        }
    }
    GEN_ROWSUM(__expf(acc[mt][0][q]) + __expf(acc[mt][1][q]) +
               __expf(acc[mt][2][q]) + __expf(acc[mt][3][q]));
}

// ---------------------------------------------------------------------------
// Fused normalize + copy-scatter, bf16-logit variant.
// ---------------------------------------------------------------------------
__global__ __launch_bounds__(256) void k_finsc_bf(const int* __restrict__ src,
                                                  const float* __restrict__ probs,
                                                  const float* __restrict__ gate,
                                                  const float* __restrict__ rowsum,
                                                  const short* __restrict__ L16,
                                                  float* __restrict__ out) {
    int row = blockIdx.x;
    int b = row >> 8;
    int tid = threadIdx.x;
    float g = gate[row];
    float inv = g / rowsum[row];
    const short* lp = L16 + (size_t)row * VV;
    float* op = out + (size_t)row * VV;

    for (int i = tid; i < VV / 8; i += 256) {
        s16x8 l8 = *(const s16x8*)&lp[i * 8];
        float4 o0, o1;
        o0.x = __expf(bf2f(l8[0])) * inv; o0.y = __expf(bf2f(l8[1])) * inv;
        o0.z = __expf(bf2f(l8[2])) * inv; o0.w = __expf(bf2f(l8[3])) * inv;
        o1.x = __expf(bf2f(l8[4])) * inv; o1.y = __expf(bf2f(l8[5])) * inv;
        o1.z = __expf(bf2f(l8[6])) * inv; o1.w = __expf(bf2f(l8[7])) * inv;
        *(float4*)&op[i * 8] = o0;
        *(float4*)&op[i * 8 + 4] = o1;
    }
    __syncthreads();

    float og = 1.0f - g;
#pragma unroll
    for (int h = 0; h < 2; ++h) {
        int s = tid + h * 256;
        float val = og * probs[(size_t)row * SS + s];
        atomicAdd(&op[src[b * SS + s]], val);
    }
}

// f32-logit variant
__global__ __launch_bounds__(256) void k_finsc(const int* __restrict__ src,
                                               const float* __restrict__ probs,
                                               const float* __restrict__ gate,
                                               const float* __restrict__ rowsum,
                                               float* __restrict__ out) {
    int row = blockIdx.x;
    int b = row >> 8;
    int tid = threadIdx.x;
    float g = gate[row];
    float inv = g / rowsum[row];
    float* op = out + (size_t)row * VV;

    for (int i = tid; i < VV / 4; i += 256) {
        float4 l = *(const float4*)&op[i * 4];
        l.x = __expf(l.x) * inv;
        l.y = __expf(l.y) * inv;
        l.z = __expf(l.z) * inv;
        l.w = __expf(l.w) * inv;
        *(float4*)&op[i * 4] = l;
    }
    __syncthreads();

    float og = 1.0f - g;
#pragma unroll
    for (int h = 0; h < 2; ++h) {
        int s = tid + h * 256;
        float val = og * probs[(size_t)row * SS + s];
        atomicAdd(&op[src[b * SS + s]], val);
    }
}

// ---------------------------------------------------------------------------
extern "C" void kernel_launch(void* const* d_in, const int* in_sizes, int n_in,
                              void* d_out, int out_size, void* d_ws, size_t ws_size,
                              hipStream_t stream) {
    const int*   src    = (const int*)d_in[0];
    const int*   tgt    = (const int*)d_in[1];
    const float* emb    = (const float*)d_in[2];
    const float* pos    = (const float*)d_in[3];
    const float* ef_wih = (const float*)d_in[4];
    const float* ef_whh = (const float*)d_in[5];
    const float* ef_bih = (const float*)d_in[6];
    const float* ef_bhh = (const float*)d_in[7];
    const float* eb_wih = (const float*)d_in[8];
    const float* eb_whh = (const float*)d_in[9];
    const float* eb_bih = (const float*)d_in[10];
    const float* eb_bhh = (const float*)d_in[11];
    const float* d_wih  = (const float*)d_in[12];
    const float* d_whh  = (const float*)d_in[13];
    const float* d_bih  = (const float*)d_in[14];
    const float* d_bhh  = (const float*)d_in[15];
    const float* Wq     = (const float*)d_in[16];
    const float* Wk     = (const float*)d_in[17];
    const float* Wgen   = (const float*)d_in[18];
    const float* bgen   = (const float*)d_in[19];
    const float* Wgate  = (const float*)d_in[20];
    const float* bgate  = (const float*)d_in[21];
    float* out = (float*)d_out;
    float* ws  = (float*)d_ws;

    float* ef_x     = ws;
    float* eb_x     = ef_x + (size_t)BB * SS * D3;
    float* d_x      = eb_x + (size_t)BB * SS * D3;
    float* enc_out  = d_x + (size_t)BB * TT * D3;
    float* dec_out  = enc_out + (size_t)BB * SS * D2;
    float* Qb       = dec_out + (size_t)BB * TT * DIM;
    float* Kb       = Qb + (size_t)BB * TT * DIM;
    float* probs    = Kb + (size_t)BB * SS * DIM;
    short* cmb_bf   = (short*)(probs + (size_t)BB * TT * SS);
    float* gate     = (float*)(cmb_bf + (size_t)BB * TT * D3);
    float* rowsum   = gate + 1024;
    short* wgen_bf  = (short*)(rowsum + 1024);
    short* logit_bf = wgen_bf + (size_t)VV * D3;
    const bool use_bf  = ws_size >= (size_t)((char*)(wgen_bf + (size_t)VV * D3) - (char*)d_ws);
    const bool use_lbf = ws_size >= (size_t)((char*)(logit_bf + (size_t)VV * BB * TT) - (char*)d_ws);

    // 1. input projections with fused embedding (bf16 MFMA)
    {
        PDesc e0 = {src, ef_wih, ef_bih, ef_x, BB * SS, SS - 1};
        PDesc e1 = {src, eb_wih, eb_bih, eb_x, BB * SS, SS - 1};
        PDesc e2 = {tgt, d_wih, d_bih, d_x, BB * TT, TT - 1};
        k_proj<<<dim3(D3 / 128, BB * SS / 256, 3), 512, 0, stream>>>(emb, pos, e0, e1, e2);
    }

    // 2. recurrences + Wgen cvt + rowsum zero; 88KB dyn-LDS -> 1 block/CU
    {
        int ncvtb = (int)((NCVT8 + 511) / 512);
        k_gru<<<3 + ncvtb, 512, GRU_LDS, stream>>>(ef_x, eb_x, d_x,
                                                   ef_whh, ef_bhh, eb_whh, eb_bhh, d_whh, d_bhh,
                                                   enc_out, dec_out,
                                                   Wgen, wgen_bf, rowsum, use_bf ? 1 : 0);
    }

    // 3. Q/K projections (bf16 MFMA)
    {
        QDesc q0 = {dec_out, DIM, Wq, Qb, BB * TT};
        QDesc q1 = {enc_out, D2, Wk, Kb, BB * SS};
        k_qk<<<dim3(DIM / 128, BB * SS / 256, 2), 512, 0, stream>>>(q0, q1);
    }

    // 4. attention + combined(bf16) + gate
    k_attn<<<BB * TT, 512, 0, stream>>>(Qb, Kb, enc_out, dec_out, Wgate, bgate,
                                        probs, cmb_bf, gate);

    // 5+6. generator logits + rowsum, then normalize + copy-scatter
    dim3 gg(VV / 128, (BB * TT) / 256);
    if (use_lbf) {
        k_genb<<<gg, 512, 0, stream>>>(cmb_bf, wgen_bf, bgen, logit_bf, rowsum);
        k_finsc_bf<<<BB * TT, 256, 0, stream>>>(src, probs, gate, rowsum, logit_bf, out);
    } else if (use_bf) {
        k_gen_bf<<<gg, 512, 0, stream>>>(cmb_bf, wgen_bf, bgen, out, rowsum);
        k_finsc<<<BB * TT, 256, 0, stream>>>(src, probs, gate, rowsum, out);
    } else {
        k_gen<<<gg, 512, 0, stream>>>(cmb_bf, Wgen, bgen, out, rowsum);
        k_finsc<<<BB * TT, 256, 0, stream>>>(src, probs, gate, rowsum, out);
    }
}